// Round 4
// baseline (493.169 us; speedup 1.0000x reference)
//
#include <hip/hip_runtime.h>
#include <stdint.h>
#include <math.h>

// ---------------------------------------------------------------------------
// MultiHeadAttention: B=4, S=2048, D=1024, H=16, dk=64
// Raw-reshape head split: head (b,h) = rows [b*2048+h*128, +128) of the
// projected [8192][1024] matrix, reinterpreted as [2048][64].
// R6: R5 with the P-through-LDS path cost-reduced:
//   - split-g P: PV done per 32-key group; per-wave P tile [32 q][32 key] f16
//     (2KB). Total LDS 48->40KB -> 4 blocks/CU (was 3). MFMA(g0) overlaps
//     pack(g1).
//   - bank-true P swizzle: rows are 64B so bank = 16(q&1)+4seg+2hl; swizzle
//     seg^((q>>1)&3) -> b64 writes 2-way (free), b128 reads conflict-free.
//   - v_cvt_pkrtz pack (1 op / 2 values) instead of scalar RNE (3 ops).
// Correctness: P write (true-key C-layout) and P read share one addressing
// convention == V A-frag convention -> unknown k-slot permutations cancel
// between the PV operands (same argument that made R5 pass).
// ---------------------------------------------------------------------------

typedef __attribute__((ext_vector_type(8))) short short8;
typedef __attribute__((ext_vector_type(4))) float f32x4;
typedef __attribute__((ext_vector_type(16))) float f32x16;
typedef __attribute__((ext_vector_type(2))) unsigned int u32x2;
typedef __attribute__((ext_vector_type(4))) unsigned int u32x4;
typedef __attribute__((ext_vector_type(8))) _Float16 half8;

__device__ __forceinline__ unsigned short bf16rne(float f) {
  unsigned int u = __builtin_bit_cast(unsigned int, f);
  unsigned int r = u + 0x7FFFu + ((u >> 16) & 1u);
  return (unsigned short)(r >> 16);
}

// async global->LDS, 16B per lane. LDS dest must be wave-uniform base + lane*16.
__device__ __forceinline__ void gld_lds16(const void* g, void* l) {
  typedef __attribute__((address_space(3))) unsigned int lds_u32;
  typedef const __attribute__((address_space(1))) unsigned int glb_u32;
  __builtin_amdgcn_global_load_lds((glb_u32*)(uintptr_t)g,
                                   (lds_u32*)(unsigned int)(uintptr_t)l,
                                   16, 0, 0);
}

// pack two f32 -> one u32 of two f16 (RTZ, single v_cvt_pkrtz_f16_f32)
__device__ __forceinline__ unsigned pkrtz(float a, float b) {
  auto h = __builtin_amdgcn_cvt_pkrtz(a, b);  // __fp16 ext_vector_type(2)
  return __builtin_bit_cast(unsigned, h);
}

// ---------------------------------------------------------------------------
// fp32 -> bf16 convert for Q,K,V   (3 x 8192 x 1024)
// ---------------------------------------------------------------------------
__global__ void convert_x_kernel(const float* __restrict__ Q,
                                 const float* __restrict__ K,
                                 const float* __restrict__ V,
                                 unsigned short* __restrict__ Xb) {
  const int z = blockIdx.y;
  const float* src = (z == 0) ? Q : (z == 1) ? K : V;
  const size_t i0 = ((size_t)blockIdx.x * 256 + threadIdx.x) * 8;
  const f32x4 a = *(const f32x4*)(src + i0);
  const f32x4 c = *(const f32x4*)(src + i0 + 4);
  u32x4 o;
  o[0] = (unsigned)bf16rne(a[0]) | ((unsigned)bf16rne(a[1]) << 16);
  o[1] = (unsigned)bf16rne(a[2]) | ((unsigned)bf16rne(a[3]) << 16);
  o[2] = (unsigned)bf16rne(c[0]) | ((unsigned)bf16rne(c[1]) << 16);
  o[3] = (unsigned)bf16rne(c[2]) | ((unsigned)bf16rne(c[3]) << 16);
  *(u32x4*)(Xb + (size_t)z * 8388608 + i0) = o;
}

// ---------------------------------------------------------------------------
// W [K=1024][N=1024] fp32 -> Wt [N][K] bf16 (transposed so GEMMs are A*B^T)
// ---------------------------------------------------------------------------
__global__ void convert_w_kernel(const float* __restrict__ W0,
                                 const float* __restrict__ W1,
                                 const float* __restrict__ W2,
                                 const float* __restrict__ W3,
                                 unsigned short* __restrict__ Wt) {
  const int z = blockIdx.z;
  const float* W = (z == 0) ? W0 : (z == 1) ? W1 : (z == 2) ? W2 : W3;
  unsigned short* dst = Wt + (size_t)z * 1048576;
  __shared__ float tile[32][33];
  const int tx = threadIdx.x & 31, ty = threadIdx.x >> 5;
  const int k0 = blockIdx.x * 32, n0 = blockIdx.y * 32;
#pragma unroll
  for (int yy = 0; yy < 32; yy += 8)
    tile[ty + yy][tx] = W[(size_t)(k0 + ty + yy) * 1024 + n0 + tx];
  __syncthreads();
#pragma unroll
  for (int yy = 0; yy < 32; yy += 8)
    dst[(size_t)(n0 + ty + yy) * 1024 + k0 + tx] = bf16rne(tile[tx][ty + yy]);
}

// ---------------------------------------------------------------------------
// GEMM (m97 structure): C[z] = A[z][8192x1024] * Bt[z][1024x1024]^T
// ---------------------------------------------------------------------------
__global__ __launch_bounds__(256, 2) void gemm_bt_kernel(
    const unsigned short* __restrict__ A, const unsigned short* __restrict__ Bt,
    unsigned short* __restrict__ Cbf, float* __restrict__ Cf32, float scaleZ0) {
  constexpr int K = 1024, N = 1024;
  const int z = blockIdx.z;
  const unsigned short* Ab = A + (size_t)z * 8192 * 1024;
  const unsigned short* Bb = Bt + (size_t)z * 1024 * 1024;
  const int tid = threadIdx.x;
  const int lane = tid & 63;
  const int w = tid >> 6;
  const int l15 = lane & 15, quad = lane >> 4;
  const int rowBase = blockIdx.x * 128;
  const int colBase = blockIdx.y * 128;
  const int wrow = (w >> 1) * 64;
  const int wcol = (w & 1) * 64;
  __shared__ __align__(16) unsigned short As[128 * 32];
  __shared__ __align__(16) unsigned short Bs[128 * 32];

  const f32x4 z4 = {0.0f, 0.0f, 0.0f, 0.0f};
  f32x4 acc[4][4];
#pragma unroll
  for (int i = 0; i < 4; i++)
#pragma unroll
    for (int j = 0; j < 4; j++) acc[i][j] = z4;

  const int s0 = tid, s1 = tid + 256;
  const int rA0 = s0 >> 2, cA0 = (s0 & 3) * 8;
  const int rA1 = s1 >> 2, cA1 = (s1 & 3) * 8;

  for (int k0 = 0; k0 < K; k0 += 32) {
    gld_lds16(Ab + (size_t)(rowBase + rA0) * K + k0 + cA0, (void*)(As + s0 * 8));
    gld_lds16(Ab + (size_t)(rowBase + rA1) * K + k0 + cA1, (void*)(As + s1 * 8));
    gld_lds16(Bb + (size_t)(colBase + rA0) * K + k0 + cA0, (void*)(Bs + s0 * 8));
    gld_lds16(Bb + (size_t)(colBase + rA1) * K + k0 + cA1, (void*)(Bs + s1 * 8));
    __syncthreads();
    short8 af[4], bfr[4];
#pragma unroll
    for (int i = 0; i < 4; i++)
      af[i] = *(const short8*)(As + (wrow + i * 16 + l15) * 32 + quad * 8);
#pragma unroll
    for (int j = 0; j < 4; j++)
      bfr[j] = *(const short8*)(Bs + (wcol + j * 16 + l15) * 32 + quad * 8);
#pragma unroll
    for (int i = 0; i < 4; i++)
#pragma unroll
      for (int j = 0; j < 4; j++)
        acc[i][j] =
            __builtin_amdgcn_mfma_f32_16x16x32_bf16(af[i], bfr[j], acc[i][j], 0, 0, 0);
    __syncthreads();
  }

  const float sc = (z == 0) ? scaleZ0 : 1.0f;
#pragma unroll
  for (int i = 0; i < 4; i++) {
#pragma unroll
    for (int j = 0; j < 4; j++) {
#pragma unroll
      for (int r = 0; r < 4; r++) {
        const int row = rowBase + wrow + i * 16 + quad * 4 + r;
        const int col = colBase + wcol + j * 16 + l15;
        const float v = acc[i][j][r] * sc;
        if (Cbf != nullptr) {
          Cbf[(size_t)z * 8192 * 1024 + (size_t)row * N + col] = bf16rne(v);
        } else {
          Cf32[(size_t)row * N + col] = v;
        }
      }
    }
  }
}

// ---------------------------------------------------------------------------
// V transpose: lin_v head (b,h) [2048][64] bf16 -> Vt[bh][64][2048] f16.
// ---------------------------------------------------------------------------
__global__ void vtrans_kernel(const unsigned short* __restrict__ linv,
                              unsigned short* __restrict__ Vt) {
  const int st = blockIdx.x, bh = blockIdx.y;
  const unsigned short* vp = linv + (size_t)bh * 131072;
  __shared__ unsigned short tile[64 * 136];
  const int tid = threadIdx.x;
#pragma unroll
  for (int it = 0; it < 4; it++) {
    const int idx = it * 256 + tid;        // 0..1023
    const int s = idx >> 3, d0 = (idx & 7) * 8;
    const u32x4 vv = *(const u32x4*)(vp + (size_t)(st * 128 + s) * 64 + d0);
#pragma unroll
    for (int m = 0; m < 4; m++) {
      const unsigned lo = vv[m] & 0xffffu, hi = vv[m] >> 16;
      const float f0 = __builtin_bit_cast(float, lo << 16);
      const float f1 = __builtin_bit_cast(float, hi << 16);
      const _Float16 h0 = (_Float16)f0, h1 = (_Float16)f1;
      tile[(d0 + 2 * m) * 136 + s] = __builtin_bit_cast(unsigned short, h0);
      tile[(d0 + 2 * m + 1) * 136 + s] = __builtin_bit_cast(unsigned short, h1);
    }
  }
  __syncthreads();
#pragma unroll
  for (int it = 0; it < 4; it++) {
    const int idx = it * 256 + tid;
    const int d = idx >> 4, s0 = (idx & 15) * 8;
    const u32x4 o = *(const u32x4*)(tile + d * 136 + s0);
    *(u32x4*)(Vt + (size_t)bh * 131072 + (size_t)d * 2048 + st * 128 + s0) = o;
  }
}

// ---------------------------------------------------------------------------
// Flash attention, 32x32 MFMA path, async-LDS double-buffered.
// Grid (bh=64, qt=16); block 256 = 4 waves; wave w owns q-rows
// [qt*128+w*32, +32); lane's q = l&31.
// LDS 40KB: Ks [2][64 key][64 dk] bf16 16KB + Vs [2][64 d][64 key] f16 16KB
// (both XOR-swizzled 16B segs, seg^(row&7)) + per-wave P tile [32 q][32 key]
// f16 2KB x4 = 8KB.  -> 4 blocks/CU.
// S^T = mfma_32x32x16_bf16(K, Q): C col = q = l&31, row = key =
// (r&3)+8*(r>>2)+4*(l>>5)  [HW-verified layout].
// PV per 32-key group g: P packed (pkrtz) and ds_written at its true key
// index (swizzle seg^((q>>1)&3): writes 2-way, reads conflict-free), then
// read back as B-fragments with the SAME convention as the V A-fragments.
// ---------------------------------------------------------------------------
__global__ __launch_bounds__(256, 4) void attn_kernel(
    const unsigned short* __restrict__ lin, const _Float16* __restrict__ Vt,
    unsigned short* __restrict__ ctxr) {
  const int bh = blockIdx.x;
  const int qt = blockIdx.y;
  const int b = bh >> 4, h = bh & 15;
  const int tid = threadIdx.x, lane = tid & 63, w = tid >> 6;
  const int l31 = lane & 31, hl = lane >> 5, x7 = l31 & 7;
  const int sw = (l31 >> 1) & 3;  // P-tile swizzle
  const size_t headOff = (size_t)(b * 2048 + h * 128) * 1024;
  const unsigned short* qp = lin + headOff;
  const unsigned short* kp = lin + 8388608 + headOff;
  const _Float16* vtp = Vt + (size_t)bh * 131072;

  __shared__ __align__(16) unsigned short smem[20480];  // 40 KB
  unsigned short(*Ks)[4096] = (unsigned short(*)[4096])smem;     // [2][4096]
  _Float16(*Vs)[4096] = (_Float16(*)[4096])(smem + 8192);        // [2][4096]
  _Float16* Pl = (_Float16*)(smem + 16384) + w * 1024;           // [32][32]

  // Staging geometry: waves 0,1 stage K (512 slots); waves 2,3 stage V.
  const int stageV = (w >= 2);
  const int wbase = (stageV ? (w - 2) : w) * 256 + lane;
  auto stage = [&](int bufn, int key0) {
#pragma unroll
    for (int i = 0; i < 4; i++) {
      const int slot = wbase + i * 64;
      const int row = slot >> 3;                 // key (K) or d (V)
      const int seg = (slot & 7) ^ (row & 7);    // un-swizzled segment
      if (!stageV) {
        gld_lds16(kp + (size_t)(key0 + row) * 64 + seg * 8,
                  (void*)(&Ks[bufn][slot * 8]));
      } else {
        gld_lds16(vtp + (size_t)row * 2048 + key0 + seg * 8,
                  (void*)(&Vs[bufn][slot * 8]));
      }
    }
  };

  // Q B-fragments (col = q = l31, k-window ks*16 + hl*8).
  const int qrow0 = qt * 128 + w * 32;
  short8 bq[4];
#pragma unroll
  for (int ks = 0; ks < 4; ks++)
    bq[ks] = *(const short8*)(qp + (size_t)(qrow0 + l31) * 64 + ks * 16 + hl * 8);

  f32x16 z16;
#pragma unroll
  for (int r = 0; r < 16; r++) z16[r] = 0.0f;
  f32x16 co[2] = {z16, z16};  // O^T: co[dt], d = dt*32+(r&3)+8*(r>>2)+4*hl
  float mrun = -INFINITY, lrun = 0.0f;

  stage(0, 0);
  __syncthreads();

  for (int kt = 0; kt < 32; kt++) {
    const int cur = kt & 1;
    if (kt < 31) stage(cur ^ 1, (kt + 1) * 64);

    // ---- S^T: 8x mfma_32x32x16_bf16 (2 key-groups x 4 dk-steps)
    f32x16 sacc[2] = {z16, z16};
    __builtin_amdgcn_s_setprio(1);
#pragma unroll
    for (int g = 0; g < 2; g++) {
#pragma unroll
      for (int ks = 0; ks < 4; ks++) {
        const int slot = (g * 32 + l31) * 8 + ((2 * ks + hl) ^ x7);
        const short8 kf = *(const short8*)(&Ks[cur][slot * 8]);
        sacc[g] =
            __builtin_amdgcn_mfma_f32_32x32x16_bf16(kf, bq[ks], sacc[g], 0, 0, 0);
      }
    }
    __builtin_amdgcn_s_setprio(0);

    // ---- V A-fragments (row = d = dt*32+l31, k-window 16*(2g+s) + hl*8):
    // 8x ds_read_b128, independent of sacc -> latency hides under softmax.
    half8 vf[2][2][2];  // [dt][g][s]
#pragma unroll
    for (int dt = 0; dt < 2; dt++)
#pragma unroll
      for (int g = 0; g < 2; g++)
#pragma unroll
        for (int s = 0; s < 2; s++) {
          const int slot = (dt * 32 + l31) * 8 + ((4 * g + 2 * s + hl) ^ x7);
          vf[dt][g][s] = *(const half8*)(&Vs[cur][slot * 8]);
        }

    // ---- online softmax (lane owns q = l31; keys split across wave halves)
    float pmax;
    {
      float tm[8];
#pragma unroll
      for (int r = 0; r < 8; r++)
        tm[r] = fmaxf(fmaxf(sacc[0][r], sacc[0][r + 8]),
                      fmaxf(sacc[1][r], sacc[1][r + 8]));
      const float a0 = fmaxf(fmaxf(tm[0], tm[1]), fmaxf(tm[2], tm[3]));
      const float a1 = fmaxf(fmaxf(tm[4], tm[5]), fmaxf(tm[6], tm[7]));
      pmax = fmaxf(a0, a1);
    }
    pmax = fmaxf(pmax, __shfl_xor(pmax, 32, 64));
    if (!__all(pmax - mrun <= 8.0f)) {  // defer-max: rescale only on real growth
      const float mnew = fmaxf(mrun, pmax);
      const float a = exp2f(mrun - mnew);
      mrun = mnew;
      lrun *= a;
#pragma unroll
      for (int r = 0; r < 16; r++) {
        co[0][r] *= a;
        co[1][r] *= a;
      }
    }
    float ls0 = 0.0f, ls1 = 0.0f, ls2 = 0.0f, ls3 = 0.0f;
#pragma unroll
    for (int g = 0; g < 2; g++) {
#pragma unroll
      for (int r = 0; r < 16; r += 4) {
        const float p0 = exp2f(sacc[g][r + 0] - mrun);
        const float p1 = exp2f(sacc[g][r + 1] - mrun);
        const float p2 = exp2f(sacc[g][r + 2] - mrun);
        const float p3 = exp2f(sacc[g][r + 3] - mrun);
        sacc[g][r + 0] = p0;
        sacc[g][r + 1] = p1;
        sacc[g][r + 2] = p2;
        sacc[g][r + 3] = p3;
        ls0 += p0;
        ls1 += p1;
        ls2 += p2;
        ls3 += p3;
      }
    }
    lrun += (ls0 + ls1) + (ls2 + ls3);

    // ---- PV per 32-key group: P -> per-wave LDS tile [32 q][32 key] f16
    // at true key index (C-layout key_in_grp = 8rg+4hl+t), swizzle
    // seg^((q>>1)&3); read back as B-fragments (same convention as V
    // A-fragments) -> 2x mfma per (dt,s).
#pragma unroll
    for (int g = 0; g < 2; g++) {
#pragma unroll
      for (int rg = 0; rg < 4; rg++) {
        u32x2 pw;
        pw[0] = pkrtz(sacc[g][4 * rg + 0], sacc[g][4 * rg + 1]);
        pw[1] = pkrtz(sacc[g][4 * rg + 2], sacc[g][4 * rg + 3]);
        *(u32x2*)(Pl + l31 * 32 + ((rg ^ sw) * 8) + hl * 4) = pw;
      }
      half8 pf[2];
#pragma unroll
      for (int s = 0; s < 2; s++)
        pf[s] = *(const half8*)(Pl + l31 * 32 + (((2 * s + hl) ^ sw) * 8));
      __builtin_amdgcn_s_setprio(1);
#pragma unroll
      for (int dt = 0; dt < 2; dt++)
#pragma unroll
        for (int s = 0; s < 2; s++)
          co[dt] = __builtin_amdgcn_mfma_f32_32x32x16_f16(vf[dt][g][s], pf[s],
                                                          co[dt], 0, 0, 0);
      __builtin_amdgcn_s_setprio(0);
    }
    __syncthreads();  // drains stage loads; separates buffer reuse
  }

  // ---- epilogue: normalize, transpose via LDS, coalesced b128 stores.
  lrun += __shfl_xor(lrun, 32, 64);
  const float inv = 1.0f / lrun;
  unsigned short* Cw = smem + w * 2304;  // per-wave 32 rows x stride 72
#pragma unroll
  for (int dt = 0; dt < 2; dt++) {
#pragma unroll
    for (int r = 0; r < 16; r++) {
      const int d = dt * 32 + (r & 3) + 8 * (r >> 2) + 4 * hl;
      Cw[l31 * 72 + d] = bf16rne(co[dt][r] * inv);
    }
  }
  __syncthreads();
#pragma unroll
  for (int it = 0; it < 4; it++) {
    const int q = it * 8 + (lane >> 3);
    const int seg = lane & 7;
    const u32x4 o = *(const u32x4*)(Cw + q * 72 + seg * 8);
    *(u32x4*)(ctxr + (size_t)(b * 2048 + qrow0 + q) * 1024 + h * 64 + seg * 8) = o;
  }
}

// ---------------------------------------------------------------------------
extern "C" void kernel_launch(void* const* d_in, const int* in_sizes, int n_in,
                              void* d_out, int out_size, void* d_ws, size_t ws_size,
                              hipStream_t stream) {
  const float* Q = (const float*)d_in[0];
  const float* K = (const float*)d_in[1];
  const float* V = (const float*)d_in[2];
  const float* WQ = (const float*)d_in[3];
  const float* WK = (const float*)d_in[4];
  const float* WV = (const float*)d_in[5];
  const float* Wfc = (const float*)d_in[6];
  float* out = (float*)d_out;

  unsigned short* ws = (unsigned short*)d_ws;
  // ws layout (ushort units):
  //   Xb   @ 0         : 3*8388608  (bf16 Q,K,V)      [dead after projections]
  //   ctxr @ 0         : 8388608    (bf16 ctx)        [overlays Xb]
  //   Vt   @ 8388608   : 8388608    (f16 V^T)         [overlays Xb]
  //   Wt   @ 25165824  : 4*1048576  (bf16 W^T: q,k,v,fc)
  //   lin  @ 29360128  : 3*8388608  (bf16 projections)
  unsigned short* Xb = ws;
  unsigned short* ctxr = ws;
  unsigned short* Vt = ws + 8388608;
  unsigned short* Wt = ws + 25165824;
  unsigned short* lin = ws + 29360128;

  convert_x_kernel<<<dim3(4096, 3), 256, 0, stream>>>(Q, K, V, Xb);
  convert_w_kernel<<<dim3(32, 32, 4), 256, 0, stream>>>(WQ, WK, WV, Wfc, Wt);
  const float qscale = 0.125f * 1.4426950408889634f;  // 1/sqrt(dk) * log2(e)
  gemm_bt_kernel<<<dim3(64, 8, 3), 256, 0, stream>>>(Xb, Wt, lin, nullptr, qscale);
  vtrans_kernel<<<dim3(16, 64), 256, 0, stream>>>(lin + 16777216, Vt);
  attn_kernel<<<dim3(64, 16), 256, 0, stream>>>(lin, (const _Float16*)Vt, ctxr);
  gemm_bt_kernel<<<dim3(64, 8, 1), 256, 0, stream>>>(ctxr, Wt + 3 * 1048576, nullptr,
                                                     out, 1.0f);
}

// Round 5
// 422.451 us; speedup vs baseline: 1.1674x; 1.1674x over previous
//
#include <hip/hip_runtime.h>
#include <stdint.h>
#include <math.h>

// ---------------------------------------------------------------------------
// MultiHeadAttention: B=4, S=2048, D=1024, H=16, dk=64
// Raw-reshape head split: head (b,h) = rows [b*2048+h*128, +128) of the
// projected [8192][1024] matrix, reinterpreted as [2048][64].
// R7 = R5 geometry (48KB LDS, 3 blocks/CU -- the L2-resident regime; R6's
// 40KB/4-block config quadrupled HBM fetch via per-XCD K/V thrash) plus the
// occupancy-neutral R6 wins:
//   - v_cvt_pkrtz P pack (16 VALU/tile vs 48 scalar-RNE)
//   - split-g PV: pack+write one 32-key half, read+MFMA it while the other
//     half packs (P LDS round-trip hides under MFMA). Addressing is byte-
//     identical to R5's proven convention; per-row g-halves are closed under
//     the XOR swizzle, so correctness is inherited.
// Everything else from R5: 32x32x16 MFMA path, single-q-per-lane softmax
// (one shfl_xor(32)/tile), defer-max THR=8, layout-proof P-through-LDS,
// async global_load_lds double-buffered K/V staging, one barrier per tile,
// LDS-transpose epilogue.
// ---------------------------------------------------------------------------

typedef __attribute__((ext_vector_type(8))) short short8;
typedef __attribute__((ext_vector_type(4))) float f32x4;
typedef __attribute__((ext_vector_type(16))) float f32x16;
typedef __attribute__((ext_vector_type(2))) unsigned int u32x2;
typedef __attribute__((ext_vector_type(4))) unsigned int u32x4;
typedef __attribute__((ext_vector_type(8))) _Float16 half8;

__device__ __forceinline__ unsigned short bf16rne(float f) {
  unsigned int u = __builtin_bit_cast(unsigned int, f);
  unsigned int r = u + 0x7FFFu + ((u >> 16) & 1u);
  return (unsigned short)(r >> 16);
}

// async global->LDS, 16B per lane. LDS dest must be wave-uniform base + lane*16.
__device__ __forceinline__ void gld_lds16(const void* g, void* l) {
  typedef __attribute__((address_space(3))) unsigned int lds_u32;
  typedef const __attribute__((address_space(1))) unsigned int glb_u32;
  __builtin_amdgcn_global_load_lds((glb_u32*)(uintptr_t)g,
                                   (lds_u32*)(unsigned int)(uintptr_t)l,
                                   16, 0, 0);
}

// pack two f32 -> one u32 of two f16 (RTZ, single v_cvt_pkrtz_f16_f32)
__device__ __forceinline__ unsigned pkrtz(float a, float b) {
  auto h = __builtin_amdgcn_cvt_pkrtz(a, b);  // __fp16 ext_vector_type(2)
  return __builtin_bit_cast(unsigned, h);
}

// ---------------------------------------------------------------------------
// fp32 -> bf16 convert for Q,K,V   (3 x 8192 x 1024)
// ---------------------------------------------------------------------------
__global__ void convert_x_kernel(const float* __restrict__ Q,
                                 const float* __restrict__ K,
                                 const float* __restrict__ V,
                                 unsigned short* __restrict__ Xb) {
  const int z = blockIdx.y;
  const float* src = (z == 0) ? Q : (z == 1) ? K : V;
  const size_t i0 = ((size_t)blockIdx.x * 256 + threadIdx.x) * 8;
  const f32x4 a = *(const f32x4*)(src + i0);
  const f32x4 c = *(const f32x4*)(src + i0 + 4);
  u32x4 o;
  o[0] = (unsigned)bf16rne(a[0]) | ((unsigned)bf16rne(a[1]) << 16);
  o[1] = (unsigned)bf16rne(a[2]) | ((unsigned)bf16rne(a[3]) << 16);
  o[2] = (unsigned)bf16rne(c[0]) | ((unsigned)bf16rne(c[1]) << 16);
  o[3] = (unsigned)bf16rne(c[2]) | ((unsigned)bf16rne(c[3]) << 16);
  *(u32x4*)(Xb + (size_t)z * 8388608 + i0) = o;
}

// ---------------------------------------------------------------------------
// W [K=1024][N=1024] fp32 -> Wt [N][K] bf16 (transposed so GEMMs are A*B^T)
// ---------------------------------------------------------------------------
__global__ void convert_w_kernel(const float* __restrict__ W0,
                                 const float* __restrict__ W1,
                                 const float* __restrict__ W2,
                                 const float* __restrict__ W3,
                                 unsigned short* __restrict__ Wt) {
  const int z = blockIdx.z;
  const float* W = (z == 0) ? W0 : (z == 1) ? W1 : (z == 2) ? W2 : W3;
  unsigned short* dst = Wt + (size_t)z * 1048576;
  __shared__ float tile[32][33];
  const int tx = threadIdx.x & 31, ty = threadIdx.x >> 5;
  const int k0 = blockIdx.x * 32, n0 = blockIdx.y * 32;
#pragma unroll
  for (int yy = 0; yy < 32; yy += 8)
    tile[ty + yy][tx] = W[(size_t)(k0 + ty + yy) * 1024 + n0 + tx];
  __syncthreads();
#pragma unroll
  for (int yy = 0; yy < 32; yy += 8)
    dst[(size_t)(n0 + ty + yy) * 1024 + k0 + tx] = bf16rne(tile[tx][ty + yy]);
}

// ---------------------------------------------------------------------------
// GEMM (m97 structure): C[z] = A[z][8192x1024] * Bt[z][1024x1024]^T
// ---------------------------------------------------------------------------
__global__ __launch_bounds__(256, 2) void gemm_bt_kernel(
    const unsigned short* __restrict__ A, const unsigned short* __restrict__ Bt,
    unsigned short* __restrict__ Cbf, float* __restrict__ Cf32, float scaleZ0) {
  constexpr int K = 1024, N = 1024;
  const int z = blockIdx.z;
  const unsigned short* Ab = A + (size_t)z * 8192 * 1024;
  const unsigned short* Bb = Bt + (size_t)z * 1024 * 1024;
  const int tid = threadIdx.x;
  const int lane = tid & 63;
  const int w = tid >> 6;
  const int l15 = lane & 15, quad = lane >> 4;
  const int rowBase = blockIdx.x * 128;
  const int colBase = blockIdx.y * 128;
  const int wrow = (w >> 1) * 64;
  const int wcol = (w & 1) * 64;
  __shared__ __align__(16) unsigned short As[128 * 32];
  __shared__ __align__(16) unsigned short Bs[128 * 32];

  const f32x4 z4 = {0.0f, 0.0f, 0.0f, 0.0f};
  f32x4 acc[4][4];
#pragma unroll
  for (int i = 0; i < 4; i++)
#pragma unroll
    for (int j = 0; j < 4; j++) acc[i][j] = z4;

  const int s0 = tid, s1 = tid + 256;
  const int rA0 = s0 >> 2, cA0 = (s0 & 3) * 8;
  const int rA1 = s1 >> 2, cA1 = (s1 & 3) * 8;

  for (int k0 = 0; k0 < K; k0 += 32) {
    gld_lds16(Ab + (size_t)(rowBase + rA0) * K + k0 + cA0, (void*)(As + s0 * 8));
    gld_lds16(Ab + (size_t)(rowBase + rA1) * K + k0 + cA1, (void*)(As + s1 * 8));
    gld_lds16(Bb + (size_t)(colBase + rA0) * K + k0 + cA0, (void*)(Bs + s0 * 8));
    gld_lds16(Bb + (size_t)(colBase + rA1) * K + k0 + cA1, (void*)(Bs + s1 * 8));
    __syncthreads();
    short8 af[4], bfr[4];
#pragma unroll
    for (int i = 0; i < 4; i++)
      af[i] = *(const short8*)(As + (wrow + i * 16 + l15) * 32 + quad * 8);
#pragma unroll
    for (int j = 0; j < 4; j++)
      bfr[j] = *(const short8*)(Bs + (wcol + j * 16 + l15) * 32 + quad * 8);
#pragma unroll
    for (int i = 0; i < 4; i++)
#pragma unroll
      for (int j = 0; j < 4; j++)
        acc[i][j] =
            __builtin_amdgcn_mfma_f32_16x16x32_bf16(af[i], bfr[j], acc[i][j], 0, 0, 0);
    __syncthreads();
  }

  const float sc = (z == 0) ? scaleZ0 : 1.0f;
#pragma unroll
  for (int i = 0; i < 4; i++) {
#pragma unroll
    for (int j = 0; j < 4; j++) {
#pragma unroll
      for (int r = 0; r < 4; r++) {
        const int row = rowBase + wrow + i * 16 + quad * 4 + r;
        const int col = colBase + wcol + j * 16 + l15;
        const float v = acc[i][j][r] * sc;
        if (Cbf != nullptr) {
          Cbf[(size_t)z * 8192 * 1024 + (size_t)row * N + col] = bf16rne(v);
        } else {
          Cf32[(size_t)row * N + col] = v;
        }
      }
    }
  }
}

// ---------------------------------------------------------------------------
// V transpose: lin_v head (b,h) [2048][64] bf16 -> Vt[bh][64][2048] f16.
// ---------------------------------------------------------------------------
__global__ void vtrans_kernel(const unsigned short* __restrict__ linv,
                              unsigned short* __restrict__ Vt) {
  const int st = blockIdx.x, bh = blockIdx.y;
  const unsigned short* vp = linv + (size_t)bh * 131072;
  __shared__ unsigned short tile[64 * 136];
  const int tid = threadIdx.x;
#pragma unroll
  for (int it = 0; it < 4; it++) {
    const int idx = it * 256 + tid;        // 0..1023
    const int s = idx >> 3, d0 = (idx & 7) * 8;
    const u32x4 vv = *(const u32x4*)(vp + (size_t)(st * 128 + s) * 64 + d0);
#pragma unroll
    for (int m = 0; m < 4; m++) {
      const unsigned lo = vv[m] & 0xffffu, hi = vv[m] >> 16;
      const float f0 = __builtin_bit_cast(float, lo << 16);
      const float f1 = __builtin_bit_cast(float, hi << 16);
      const _Float16 h0 = (_Float16)f0, h1 = (_Float16)f1;
      tile[(d0 + 2 * m) * 136 + s] = __builtin_bit_cast(unsigned short, h0);
      tile[(d0 + 2 * m + 1) * 136 + s] = __builtin_bit_cast(unsigned short, h1);
    }
  }
  __syncthreads();
#pragma unroll
  for (int it = 0; it < 4; it++) {
    const int idx = it * 256 + tid;
    const int d = idx >> 4, s0 = (idx & 15) * 8;
    const u32x4 o = *(const u32x4*)(tile + d * 136 + s0);
    *(u32x4*)(Vt + (size_t)bh * 131072 + (size_t)d * 2048 + st * 128 + s0) = o;
  }
}

// ---------------------------------------------------------------------------
// Flash attention, 32x32 MFMA path, async-LDS double-buffered.
// Grid (bh=64, qt=16); block 256 = 4 waves; wave w owns q-rows
// [qt*128+w*32, +32); lane's q = l&31.
// LDS 48KB (3 blocks/CU -- keeps per-XCD K/V L2-resident; DO NOT shrink to
// 40KB: 4 blocks/CU thrashes L2, fetch 45MB->198MB, attn +60us [R6]):
// Ks [2][64 key][64 dk] bf16 16KB + Vs [2][64 d][64 key] f16 16KB (both
// XOR-swizzled 16B segs, seg^(row&7)) + per-wave P tile [32 q][64 key] f16
// 4KB x4 = 16KB.
// S^T = mfma_32x32x16_bf16(K, Q): C col = q = l&31, row = key =
// (r&3)+8*(r>>2)+4*(l>>5)  [HW-verified layout].
// PV split per 32-key group g: P packed (pkrtz) and ds_written at its true
// key index, read back as B-fragments with the SAME convention as the V
// A-fragments (unknown k-slot permutations cancel between PV operands);
// group g's MFMAs overlap group g+1's pack.
// ---------------------------------------------------------------------------
__global__ __launch_bounds__(256, 3) void attn_kernel(
    const unsigned short* __restrict__ lin, const _Float16* __restrict__ Vt,
    unsigned short* __restrict__ ctxr) {
  const int bh = blockIdx.x;
  const int qt = blockIdx.y;
  const int b = bh >> 4, h = bh & 15;
  const int tid = threadIdx.x, lane = tid & 63, w = tid >> 6;
  const int l31 = lane & 31, hl = lane >> 5, x7 = l31 & 7;
  const size_t headOff = (size_t)(b * 2048 + h * 128) * 1024;
  const unsigned short* qp = lin + headOff;
  const unsigned short* kp = lin + 8388608 + headOff;
  const _Float16* vtp = Vt + (size_t)bh * 131072;

  __shared__ __align__(16) unsigned short smem[24576];  // 48 KB
  unsigned short(*Ks)[4096] = (unsigned short(*)[4096])smem;     // [2][4096]
  _Float16(*Vs)[4096] = (_Float16(*)[4096])(smem + 8192);        // [2][4096]
  _Float16* Pl = (_Float16*)(smem + 16384) + w * 2048;           // [32][64]

  // Staging geometry: waves 0,1 stage K (512 slots); waves 2,3 stage V.
  const int stageV = (w >= 2);
  const int wbase = (stageV ? (w - 2) : w) * 256 + lane;
  auto stage = [&](int bufn, int key0) {
#pragma unroll
    for (int i = 0; i < 4; i++) {
      const int slot = wbase + i * 64;
      const int row = slot >> 3;                 // key (K) or d (V)
      const int seg = (slot & 7) ^ (row & 7);    // un-swizzled segment
      if (!stageV) {
        gld_lds16(kp + (size_t)(key0 + row) * 64 + seg * 8,
                  (void*)(&Ks[bufn][slot * 8]));
      } else {
        gld_lds16(vtp + (size_t)row * 2048 + key0 + seg * 8,
                  (void*)(&Vs[bufn][slot * 8]));
      }
    }
  };

  // Q B-fragments (col = q = l31, k-window ks*16 + hl*8).
  const int qrow0 = qt * 128 + w * 32;
  short8 bq[4];
#pragma unroll
  for (int ks = 0; ks < 4; ks++)
    bq[ks] = *(const short8*)(qp + (size_t)(qrow0 + l31) * 64 + ks * 16 + hl * 8);

  f32x16 z16;
#pragma unroll
  for (int r = 0; r < 16; r++) z16[r] = 0.0f;
  f32x16 co[2] = {z16, z16};  // O^T: co[dt], d = dt*32+(r&3)+8*(r>>2)+4*hl
  float mrun = -INFINITY, lrun = 0.0f;

  stage(0, 0);
  __syncthreads();

  for (int kt = 0; kt < 32; kt++) {
    const int cur = kt & 1;
    if (kt < 31) stage(cur ^ 1, (kt + 1) * 64);

    // ---- S^T: 8x mfma_32x32x16_bf16 (2 key-groups x 4 dk-steps)
    f32x16 sacc[2] = {z16, z16};
    __builtin_amdgcn_s_setprio(1);
#pragma unroll
    for (int g = 0; g < 2; g++) {
#pragma unroll
      for (int ks = 0; ks < 4; ks++) {
        const int slot = (g * 32 + l31) * 8 + ((2 * ks + hl) ^ x7);
        const short8 kf = *(const short8*)(&Ks[cur][slot * 8]);
        sacc[g] =
            __builtin_amdgcn_mfma_f32_32x32x16_bf16(kf, bq[ks], sacc[g], 0, 0, 0);
      }
    }
    __builtin_amdgcn_s_setprio(0);

    // ---- V A-fragments (row = d = dt*32+l31, k-window 16*(2g+s) + hl*8):
    // 8x ds_read_b128, independent of sacc -> latency hides under softmax.
    half8 vf[2][2][2];  // [dt][g][s]
#pragma unroll
    for (int dt = 0; dt < 2; dt++)
#pragma unroll
      for (int g = 0; g < 2; g++)
#pragma unroll
        for (int s = 0; s < 2; s++) {
          const int slot = (dt * 32 + l31) * 8 + ((4 * g + 2 * s + hl) ^ x7);
          vf[dt][g][s] = *(const half8*)(&Vs[cur][slot * 8]);
        }

    // ---- online softmax (lane owns q = l31; keys split across wave halves)
    float pmax;
    {
      float tm[8];
#pragma unroll
      for (int r = 0; r < 8; r++)
        tm[r] = fmaxf(fmaxf(sacc[0][r], sacc[0][r + 8]),
                      fmaxf(sacc[1][r], sacc[1][r + 8]));
      const float a0 = fmaxf(fmaxf(tm[0], tm[1]), fmaxf(tm[2], tm[3]));
      const float a1 = fmaxf(fmaxf(tm[4], tm[5]), fmaxf(tm[6], tm[7]));
      pmax = fmaxf(a0, a1);
    }
    pmax = fmaxf(pmax, __shfl_xor(pmax, 32, 64));
    if (!__all(pmax - mrun <= 8.0f)) {  // defer-max: rescale only on real growth
      const float mnew = fmaxf(mrun, pmax);
      const float a = exp2f(mrun - mnew);
      mrun = mnew;
      lrun *= a;
#pragma unroll
      for (int r = 0; r < 16; r++) {
        co[0][r] *= a;
        co[1][r] *= a;
      }
    }
    float ls0 = 0.0f, ls1 = 0.0f, ls2 = 0.0f, ls3 = 0.0f;
#pragma unroll
    for (int g = 0; g < 2; g++) {
#pragma unroll
      for (int r = 0; r < 16; r += 4) {
        const float p0 = exp2f(sacc[g][r + 0] - mrun);
        const float p1 = exp2f(sacc[g][r + 1] - mrun);
        const float p2 = exp2f(sacc[g][r + 2] - mrun);
        const float p3 = exp2f(sacc[g][r + 3] - mrun);
        sacc[g][r + 0] = p0;
        sacc[g][r + 1] = p1;
        sacc[g][r + 2] = p2;
        sacc[g][r + 3] = p3;
        ls0 += p0;
        ls1 += p1;
        ls2 += p2;
        ls3 += p3;
      }
    }
    lrun += (ls0 + ls1) + (ls2 + ls3);

    // ---- PV split per 32-key group: P -> per-wave LDS tile at true key
    // index (C-layout key_in_grp = 8rg+4hl+t), then B-fragments read with
    // the same convention as the V A-fragments; g's MFMAs overlap g+1 pack.
#pragma unroll
    for (int g = 0; g < 2; g++) {
#pragma unroll
      for (int rg = 0; rg < 4; rg++) {
        u32x2 pw;
        pw[0] = pkrtz(sacc[g][4 * rg + 0], sacc[g][4 * rg + 1]);
        pw[1] = pkrtz(sacc[g][4 * rg + 2], sacc[g][4 * rg + 3]);
        *(u32x2*)(Pl + l31 * 64 + (((4 * g + rg) ^ x7) * 8) + hl * 4) = pw;
      }
      half8 pf[2];
#pragma unroll
      for (int s = 0; s < 2; s++)
        pf[s] =
            *(const half8*)(Pl + l31 * 64 + (((4 * g + 2 * s + hl) ^ x7) * 8));
      __builtin_amdgcn_s_setprio(1);
#pragma unroll
      for (int dt = 0; dt < 2; dt++)
#pragma unroll
        for (int s = 0; s < 2; s++)
          co[dt] = __builtin_amdgcn_mfma_f32_32x32x16_f16(vf[dt][g][s], pf[s],
                                                          co[dt], 0, 0, 0);
      __builtin_amdgcn_s_setprio(0);
    }
    __syncthreads();  // drains stage loads; separates buffer reuse
  }

  // ---- epilogue: normalize, transpose via LDS, coalesced b128 stores.
  lrun += __shfl_xor(lrun, 32, 64);
  const float inv = 1.0f / lrun;
  unsigned short* Cw = smem + w * 2304;  // per-wave 32 rows x stride 72
#pragma unroll
  for (int dt = 0; dt < 2; dt++) {
#pragma unroll
    for (int r = 0; r < 16; r++) {
      const int d = dt * 32 + (r & 3) + 8 * (r >> 2) + 4 * hl;
      Cw[l31 * 72 + d] = bf16rne(co[dt][r] * inv);
    }
  }
  __syncthreads();
#pragma unroll
  for (int it = 0; it < 4; it++) {
    const int q = it * 8 + (lane >> 3);
    const int seg = lane & 7;
    const u32x4 o = *(const u32x4*)(Cw + q * 72 + seg * 8);
    *(u32x4*)(ctxr + (size_t)(b * 2048 + qrow0 + q) * 1024 + h * 64 + seg * 8) = o;
  }
}

// ---------------------------------------------------------------------------
extern "C" void kernel_launch(void* const* d_in, const int* in_sizes, int n_in,
                              void* d_out, int out_size, void* d_ws, size_t ws_size,
                              hipStream_t stream) {
  const float* Q = (const float*)d_in[0];
  const float* K = (const float*)d_in[1];
  const float* V = (const float*)d_in[2];
  const float* WQ = (const float*)d_in[3];
  const float* WK = (const float*)d_in[4];
  const float* WV = (const float*)d_in[5];
  const float* Wfc = (const float*)d_in[6];
  float* out = (float*)d_out;

  unsigned short* ws = (unsigned short*)d_ws;
  // ws layout (ushort units):
  //   Xb   @ 0         : 3*8388608  (bf16 Q,K,V)      [dead after projections]
  //   ctxr @ 0         : 8388608    (bf16 ctx)        [overlays Xb]
  //   Vt   @ 8388608   : 8388608    (f16 V^T)         [overlays Xb]
  //   Wt   @ 25165824  : 4*1048576  (bf16 W^T: q,k,v,fc)
  //   lin  @ 29360128  : 3*8388608  (bf16 projections)
  unsigned short* Xb = ws;
  unsigned short* ctxr = ws;
  unsigned short* Vt = ws + 8388608;
  unsigned short* Wt = ws + 25165824;
  unsigned short* lin = ws + 29360128;

  convert_x_kernel<<<dim3(4096, 3), 256, 0, stream>>>(Q, K, V, Xb);
  convert_w_kernel<<<dim3(32, 32, 4), 256, 0, stream>>>(WQ, WK, WV, Wfc, Wt);
  const float qscale = 0.125f * 1.4426950408889634f;  // 1/sqrt(dk) * log2(e)
  gemm_bt_kernel<<<dim3(64, 8, 3), 256, 0, stream>>>(Xb, Wt, lin, nullptr, qscale);
  vtrans_kernel<<<dim3(16, 64), 256, 0, stream>>>(lin + 16777216, Vt);
  attn_kernel<<<dim3(64, 16), 256, 0, stream>>>(lin, (const _Float16*)Vt, ctxr);
  gemm_bt_kernel<<<dim3(64, 8, 1), 256, 0, stream>>>(ctxr, Wt + 3 * 1048576, nullptr,
                                                     out, 1.0f);
}

// Round 6
// 378.910 us; speedup vs baseline: 1.3015x; 1.1149x over previous
//
#include <hip/hip_runtime.h>
#include <stdint.h>
#include <math.h>

// ---------------------------------------------------------------------------
// MultiHeadAttention: B=4, S=2048, D=1024, H=16, dk=64
// Raw-reshape head split: head (b,h) = rows [b*2048+h*128, +128) of the
// projected [8192][1024] matrix, reinterpreted as [2048][64].
// R8 = R7 with 64 q-rows per wave (block covers 256 q; grid (64 bh, 8 qt) =
// 512 blocks = exactly 2 resident blocks/CU, no turnover tail):
//   - K-fragments, V-fragments, staging and the tile barrier are amortized
//     over 2x the q-rows (they were ~half the per-tile cycle budget);
//     MFMA/exp/pack per score unchanged.
//   - VGPR ~210 -> __launch_bounds__(256,2); all qg loops unrolled with
//     compile-time indices (no runtime-indexed vector arrays).
// Kept from R7: 48KB LDS / L2-resident regime (R6 showed 4 blocks/CU
// thrashes L2: fetch 45->198MB), 32x32x16 MFMA path, single-q-per-lane
// softmax, defer-max THR=8, layout-proof P-through-LDS (PV operands share
// one addressing convention so unknown k-slot permutations cancel),
// pkrtz pack, split-g PV, async global_load_lds double-buffered staging,
// one barrier per tile, LDS-transpose epilogue.
// ---------------------------------------------------------------------------

typedef __attribute__((ext_vector_type(8))) short short8;
typedef __attribute__((ext_vector_type(4))) float f32x4;
typedef __attribute__((ext_vector_type(16))) float f32x16;
typedef __attribute__((ext_vector_type(2))) unsigned int u32x2;
typedef __attribute__((ext_vector_type(4))) unsigned int u32x4;
typedef __attribute__((ext_vector_type(8))) _Float16 half8;

__device__ __forceinline__ unsigned short bf16rne(float f) {
  unsigned int u = __builtin_bit_cast(unsigned int, f);
  unsigned int r = u + 0x7FFFu + ((u >> 16) & 1u);
  return (unsigned short)(r >> 16);
}

// async global->LDS, 16B per lane. LDS dest must be wave-uniform base + lane*16.
__device__ __forceinline__ void gld_lds16(const void* g, void* l) {
  typedef __attribute__((address_space(3))) unsigned int lds_u32;
  typedef const __attribute__((address_space(1))) unsigned int glb_u32;
  __builtin_amdgcn_global_load_lds((glb_u32*)(uintptr_t)g,
                                   (lds_u32*)(unsigned int)(uintptr_t)l,
                                   16, 0, 0);
}

// pack two f32 -> one u32 of two f16 (RTZ, single v_cvt_pkrtz_f16_f32)
__device__ __forceinline__ unsigned pkrtz(float a, float b) {
  auto h = __builtin_amdgcn_cvt_pkrtz(a, b);  // __fp16 ext_vector_type(2)
  return __builtin_bit_cast(unsigned, h);
}

// ---------------------------------------------------------------------------
// fp32 -> bf16 convert for Q,K,V   (3 x 8192 x 1024)
// ---------------------------------------------------------------------------
__global__ void convert_x_kernel(const float* __restrict__ Q,
                                 const float* __restrict__ K,
                                 const float* __restrict__ V,
                                 unsigned short* __restrict__ Xb) {
  const int z = blockIdx.y;
  const float* src = (z == 0) ? Q : (z == 1) ? K : V;
  const size_t i0 = ((size_t)blockIdx.x * 256 + threadIdx.x) * 8;
  const f32x4 a = *(const f32x4*)(src + i0);
  const f32x4 c = *(const f32x4*)(src + i0 + 4);
  u32x4 o;
  o[0] = (unsigned)bf16rne(a[0]) | ((unsigned)bf16rne(a[1]) << 16);
  o[1] = (unsigned)bf16rne(a[2]) | ((unsigned)bf16rne(a[3]) << 16);
  o[2] = (unsigned)bf16rne(c[0]) | ((unsigned)bf16rne(c[1]) << 16);
  o[3] = (unsigned)bf16rne(c[2]) | ((unsigned)bf16rne(c[3]) << 16);
  *(u32x4*)(Xb + (size_t)z * 8388608 + i0) = o;
}

// ---------------------------------------------------------------------------
// W [K=1024][N=1024] fp32 -> Wt [N][K] bf16 (transposed so GEMMs are A*B^T)
// ---------------------------------------------------------------------------
__global__ void convert_w_kernel(const float* __restrict__ W0,
                                 const float* __restrict__ W1,
                                 const float* __restrict__ W2,
                                 const float* __restrict__ W3,
                                 unsigned short* __restrict__ Wt) {
  const int z = blockIdx.z;
  const float* W = (z == 0) ? W0 : (z == 1) ? W1 : (z == 2) ? W2 : W3;
  unsigned short* dst = Wt + (size_t)z * 1048576;
  __shared__ float tile[32][33];
  const int tx = threadIdx.x & 31, ty = threadIdx.x >> 5;
  const int k0 = blockIdx.x * 32, n0 = blockIdx.y * 32;
#pragma unroll
  for (int yy = 0; yy < 32; yy += 8)
    tile[ty + yy][tx] = W[(size_t)(k0 + ty + yy) * 1024 + n0 + tx];
  __syncthreads();
#pragma unroll
  for (int yy = 0; yy < 32; yy += 8)
    dst[(size_t)(n0 + ty + yy) * 1024 + k0 + tx] = bf16rne(tile[tx][ty + yy]);
}

// ---------------------------------------------------------------------------
// GEMM (m97 structure): C[z] = A[z][8192x1024] * Bt[z][1024x1024]^T
// ---------------------------------------------------------------------------
__global__ __launch_bounds__(256, 2) void gemm_bt_kernel(
    const unsigned short* __restrict__ A, const unsigned short* __restrict__ Bt,
    unsigned short* __restrict__ Cbf, float* __restrict__ Cf32, float scaleZ0) {
  constexpr int K = 1024, N = 1024;
  const int z = blockIdx.z;
  const unsigned short* Ab = A + (size_t)z * 8192 * 1024;
  const unsigned short* Bb = Bt + (size_t)z * 1024 * 1024;
  const int tid = threadIdx.x;
  const int lane = tid & 63;
  const int w = tid >> 6;
  const int l15 = lane & 15, quad = lane >> 4;
  const int rowBase = blockIdx.x * 128;
  const int colBase = blockIdx.y * 128;
  const int wrow = (w >> 1) * 64;
  const int wcol = (w & 1) * 64;
  __shared__ __align__(16) unsigned short As[128 * 32];
  __shared__ __align__(16) unsigned short Bs[128 * 32];

  const f32x4 z4 = {0.0f, 0.0f, 0.0f, 0.0f};
  f32x4 acc[4][4];
#pragma unroll
  for (int i = 0; i < 4; i++)
#pragma unroll
    for (int j = 0; j < 4; j++) acc[i][j] = z4;

  const int s0 = tid, s1 = tid + 256;
  const int rA0 = s0 >> 2, cA0 = (s0 & 3) * 8;
  const int rA1 = s1 >> 2, cA1 = (s1 & 3) * 8;

  for (int k0 = 0; k0 < K; k0 += 32) {
    gld_lds16(Ab + (size_t)(rowBase + rA0) * K + k0 + cA0, (void*)(As + s0 * 8));
    gld_lds16(Ab + (size_t)(rowBase + rA1) * K + k0 + cA1, (void*)(As + s1 * 8));
    gld_lds16(Bb + (size_t)(colBase + rA0) * K + k0 + cA0, (void*)(Bs + s0 * 8));
    gld_lds16(Bb + (size_t)(colBase + rA1) * K + k0 + cA1, (void*)(Bs + s1 * 8));
    __syncthreads();
    short8 af[4], bfr[4];
#pragma unroll
    for (int i = 0; i < 4; i++)
      af[i] = *(const short8*)(As + (wrow + i * 16 + l15) * 32 + quad * 8);
#pragma unroll
    for (int j = 0; j < 4; j++)
      bfr[j] = *(const short8*)(Bs + (wcol + j * 16 + l15) * 32 + quad * 8);
#pragma unroll
    for (int i = 0; i < 4; i++)
#pragma unroll
      for (int j = 0; j < 4; j++)
        acc[i][j] =
            __builtin_amdgcn_mfma_f32_16x16x32_bf16(af[i], bfr[j], acc[i][j], 0, 0, 0);
    __syncthreads();
  }

  const float sc = (z == 0) ? scaleZ0 : 1.0f;
#pragma unroll
  for (int i = 0; i < 4; i++) {
#pragma unroll
    for (int j = 0; j < 4; j++) {
#pragma unroll
      for (int r = 0; r < 4; r++) {
        const int row = rowBase + wrow + i * 16 + quad * 4 + r;
        const int col = colBase + wcol + j * 16 + l15;
        const float v = acc[i][j][r] * sc;
        if (Cbf != nullptr) {
          Cbf[(size_t)z * 8192 * 1024 + (size_t)row * N + col] = bf16rne(v);
        } else {
          Cf32[(size_t)row * N + col] = v;
        }
      }
    }
  }
}

// ---------------------------------------------------------------------------
// V transpose: lin_v head (b,h) [2048][64] bf16 -> Vt[bh][64][2048] f16.
// ---------------------------------------------------------------------------
__global__ void vtrans_kernel(const unsigned short* __restrict__ linv,
                              unsigned short* __restrict__ Vt) {
  const int st = blockIdx.x, bh = blockIdx.y;
  const unsigned short* vp = linv + (size_t)bh * 131072;
  __shared__ unsigned short tile[64 * 136];
  const int tid = threadIdx.x;
#pragma unroll
  for (int it = 0; it < 4; it++) {
    const int idx = it * 256 + tid;        // 0..1023
    const int s = idx >> 3, d0 = (idx & 7) * 8;
    const u32x4 vv = *(const u32x4*)(vp + (size_t)(st * 128 + s) * 64 + d0);
#pragma unroll
    for (int m = 0; m < 4; m++) {
      const unsigned lo = vv[m] & 0xffffu, hi = vv[m] >> 16;
      const float f0 = __builtin_bit_cast(float, lo << 16);
      const float f1 = __builtin_bit_cast(float, hi << 16);
      const _Float16 h0 = (_Float16)f0, h1 = (_Float16)f1;
      tile[(d0 + 2 * m) * 136 + s] = __builtin_bit_cast(unsigned short, h0);
      tile[(d0 + 2 * m + 1) * 136 + s] = __builtin_bit_cast(unsigned short, h1);
    }
  }
  __syncthreads();
#pragma unroll
  for (int it = 0; it < 4; it++) {
    const int idx = it * 256 + tid;
    const int d = idx >> 4, s0 = (idx & 15) * 8;
    const u32x4 o = *(const u32x4*)(tile + d * 136 + s0);
    *(u32x4*)(Vt + (size_t)bh * 131072 + (size_t)d * 2048 + st * 128 + s0) = o;
  }
}

// ---------------------------------------------------------------------------
// Flash attention, 32x32 MFMA path, async-LDS double-buffered, 64 q/wave.
// Grid (bh=64, qt=8); block 256 = 4 waves; wave w owns q-rows
// [qt*256 + w*64, +64) as two q-groups qg=0,1 of 32; lane's q = qg*32+l31.
// LDS 48KB (3-block capacity, 2 resident blocks/CU -- L2-resident regime;
// DO NOT shrink: 4 blocks/CU thrashes L2, fetch x4 [R6]):
// Ks [2][64 key][64 dk] bf16 16KB + Vs [2][64 d][64 key] f16 16KB (both
// XOR-swizzled 16B segs, seg^(row&7)) + per-wave P tile [32 q][64 key] f16
// 4KB x4 = 16KB (reused across qg; same-wave LDS is in-order).
// S^T = mfma_32x32x16_bf16(K, Q): C col = q = l31, row = key =
// (r&3)+8*(r>>2)+4*(l>>5)  [HW-verified layout].
// K/V fragments read ONCE per tile, used by both q-groups (the R8 win).
// PV per 32-key group g: P packed (pkrtz) and ds_written at its true key
// index, read back as B-fragments with the SAME convention as the V
// A-fragments (unknown k-slot permutations cancel between PV operands).
// ---------------------------------------------------------------------------
__global__ __launch_bounds__(256, 2) void attn_kernel(
    const unsigned short* __restrict__ lin, const _Float16* __restrict__ Vt,
    unsigned short* __restrict__ ctxr) {
  const int bh = blockIdx.x;
  const int qt = blockIdx.y;
  const int b = bh >> 4, h = bh & 15;
  const int tid = threadIdx.x, lane = tid & 63, w = tid >> 6;
  const int l31 = lane & 31, hl = lane >> 5, x7 = l31 & 7;
  const size_t headOff = (size_t)(b * 2048 + h * 128) * 1024;
  const unsigned short* qp = lin + headOff;
  const unsigned short* kp = lin + 8388608 + headOff;
  const _Float16* vtp = Vt + (size_t)bh * 131072;

  __shared__ __align__(16) unsigned short smem[24576];  // 48 KB
  unsigned short(*Ks)[4096] = (unsigned short(*)[4096])smem;     // [2][4096]
  _Float16(*Vs)[4096] = (_Float16(*)[4096])(smem + 8192);        // [2][4096]
  _Float16* Pl = (_Float16*)(smem + 16384) + w * 2048;           // [32][64]

  // Staging geometry: waves 0,1 stage K (512 slots); waves 2,3 stage V.
  const int stageV = (w >= 2);
  const int wbase = (stageV ? (w - 2) : w) * 256 + lane;
  auto stage = [&](int bufn, int key0) {
#pragma unroll
    for (int i = 0; i < 4; i++) {
      const int slot = wbase + i * 64;
      const int row = slot >> 3;                 // key (K) or d (V)
      const int seg = (slot & 7) ^ (row & 7);    // un-swizzled segment
      if (!stageV) {
        gld_lds16(kp + (size_t)(key0 + row) * 64 + seg * 8,
                  (void*)(&Ks[bufn][slot * 8]));
      } else {
        gld_lds16(vtp + (size_t)row * 2048 + key0 + seg * 8,
                  (void*)(&Vs[bufn][slot * 8]));
      }
    }
  };

  // Q B-fragments (col = q = l31, k-window ks*16 + hl*8) for both q-groups.
  const int qrow0 = qt * 256 + w * 64;
  short8 bq[2][4];
#pragma unroll
  for (int qg = 0; qg < 2; qg++)
#pragma unroll
    for (int ks = 0; ks < 4; ks++)
      bq[qg][ks] = *(const short8*)(qp +
                                    (size_t)(qrow0 + qg * 32 + l31) * 64 +
                                    ks * 16 + hl * 8);

  f32x16 z16;
#pragma unroll
  for (int r = 0; r < 16; r++) z16[r] = 0.0f;
  f32x16 co[2][2] = {{z16, z16}, {z16, z16}};  // [qg][dt]
  float mrun[2] = {-INFINITY, -INFINITY};
  float lrun[2] = {0.0f, 0.0f};

  stage(0, 0);
  __syncthreads();

  for (int kt = 0; kt < 32; kt++) {
    const int cur = kt & 1;
    if (kt < 31) stage(cur ^ 1, (kt + 1) * 64);

    // ---- K fragments ONCE (8x ds_read_b128), shared by both q-groups.
    short8 kf[2][4];
#pragma unroll
    for (int g = 0; g < 2; g++)
#pragma unroll
      for (int ks = 0; ks < 4; ks++) {
        const int slot = (g * 32 + l31) * 8 + ((2 * ks + hl) ^ x7);
        kf[g][ks] = *(const short8*)(&Ks[cur][slot * 8]);
      }

    // ---- S^T: 16x mfma_32x32x16_bf16 (2 qg x 2 key-groups x 4 dk-steps)
    f32x16 sacc[2][2] = {{z16, z16}, {z16, z16}};  // [qg][g]
    __builtin_amdgcn_s_setprio(1);
#pragma unroll
    for (int qg = 0; qg < 2; qg++)
#pragma unroll
      for (int g = 0; g < 2; g++)
#pragma unroll
        for (int ks = 0; ks < 4; ks++)
          sacc[qg][g] = __builtin_amdgcn_mfma_f32_32x32x16_bf16(
              kf[g][ks], bq[qg][ks], sacc[qg][g], 0, 0, 0);
    __builtin_amdgcn_s_setprio(0);

    // ---- V A-fragments ONCE (8x ds_read_b128), shared by both q-groups.
    half8 vf[2][2][2];  // [dt][g][s]
#pragma unroll
    for (int dt = 0; dt < 2; dt++)
#pragma unroll
      for (int g = 0; g < 2; g++)
#pragma unroll
        for (int s = 0; s < 2; s++) {
          const int slot = (dt * 32 + l31) * 8 + ((4 * g + 2 * s + hl) ^ x7);
          vf[dt][g][s] = *(const half8*)(&Vs[cur][slot * 8]);
        }

    // ---- per q-group: softmax + P pack/write/read + PV
#pragma unroll
    for (int qg = 0; qg < 2; qg++) {
      float pmax;
      {
        float tm[8];
#pragma unroll
        for (int r = 0; r < 8; r++)
          tm[r] = fmaxf(fmaxf(sacc[qg][0][r], sacc[qg][0][r + 8]),
                        fmaxf(sacc[qg][1][r], sacc[qg][1][r + 8]));
        const float a0 = fmaxf(fmaxf(tm[0], tm[1]), fmaxf(tm[2], tm[3]));
        const float a1 = fmaxf(fmaxf(tm[4], tm[5]), fmaxf(tm[6], tm[7]));
        pmax = fmaxf(a0, a1);
      }
      pmax = fmaxf(pmax, __shfl_xor(pmax, 32, 64));
      if (!__all(pmax - mrun[qg] <= 8.0f)) {  // defer-max
        const float mnew = fmaxf(mrun[qg], pmax);
        const float a = exp2f(mrun[qg] - mnew);
        mrun[qg] = mnew;
        lrun[qg] *= a;
#pragma unroll
        for (int r = 0; r < 16; r++) {
          co[qg][0][r] *= a;
          co[qg][1][r] *= a;
        }
      }
      float ls0 = 0.0f, ls1 = 0.0f, ls2 = 0.0f, ls3 = 0.0f;
#pragma unroll
      for (int g = 0; g < 2; g++) {
#pragma unroll
        for (int r = 0; r < 16; r += 4) {
          const float p0 = exp2f(sacc[qg][g][r + 0] - mrun[qg]);
          const float p1 = exp2f(sacc[qg][g][r + 1] - mrun[qg]);
          const float p2 = exp2f(sacc[qg][g][r + 2] - mrun[qg]);
          const float p3 = exp2f(sacc[qg][g][r + 3] - mrun[qg]);
          sacc[qg][g][r + 0] = p0;
          sacc[qg][g][r + 1] = p1;
          sacc[qg][g][r + 2] = p2;
          sacc[qg][g][r + 3] = p3;
          ls0 += p0;
          ls1 += p1;
          ls2 += p2;
          ls3 += p3;
        }
      }
      lrun[qg] += (ls0 + ls1) + (ls2 + ls3);

      // P -> per-wave LDS tile at true key index (C-layout key_in_grp =
      // 8rg+4hl+t), then B-fragments with the V A-fragment convention;
      // g's MFMAs overlap g+1's pack. Pl reused across qg (in-order LDS).
#pragma unroll
      for (int g = 0; g < 2; g++) {
#pragma unroll
        for (int rg = 0; rg < 4; rg++) {
          u32x2 pw;
          pw[0] = pkrtz(sacc[qg][g][4 * rg + 0], sacc[qg][g][4 * rg + 1]);
          pw[1] = pkrtz(sacc[qg][g][4 * rg + 2], sacc[qg][g][4 * rg + 3]);
          *(u32x2*)(Pl + l31 * 64 + (((4 * g + rg) ^ x7) * 8) + hl * 4) = pw;
        }
        half8 pf[2];
#pragma unroll
        for (int s = 0; s < 2; s++)
          pf[s] =
              *(const half8*)(Pl + l31 * 64 + (((4 * g + 2 * s + hl) ^ x7) * 8));
        __builtin_amdgcn_s_setprio(1);
#pragma unroll
        for (int dt = 0; dt < 2; dt++)
#pragma unroll
          for (int s = 0; s < 2; s++)
            co[qg][dt] = __builtin_amdgcn_mfma_f32_32x32x16_f16(
                vf[dt][g][s], pf[s], co[qg][dt], 0, 0, 0);
        __builtin_amdgcn_s_setprio(0);
      }
    }
    __syncthreads();  // drains stage loads; separates buffer reuse
  }

  // ---- epilogue: normalize, transpose via LDS, coalesced b128 stores.
  unsigned short* Cw = smem + w * 4608;  // per-wave 64 rows x stride 72
#pragma unroll
  for (int qg = 0; qg < 2; qg++) {
    const float l = lrun[qg] + __shfl_xor(lrun[qg], 32, 64);
    const float inv = 1.0f / l;
#pragma unroll
    for (int dt = 0; dt < 2; dt++) {
#pragma unroll
      for (int r = 0; r < 16; r++) {
        const int d = dt * 32 + (r & 3) + 8 * (r >> 2) + 4 * hl;
        Cw[(qg * 32 + l31) * 72 + d] = bf16rne(co[qg][dt][r] * inv);
      }
    }
  }
  __syncthreads();
#pragma unroll
  for (int it = 0; it < 8; it++) {
    const int q = it * 8 + (lane >> 3);
    const int seg = lane & 7;
    const u32x4 o = *(const u32x4*)(Cw + q * 72 + seg * 8);
    *(u32x4*)(ctxr + (size_t)(b * 2048 + qrow0 + q) * 1024 + h * 64 + seg * 8) = o;
  }
}

// ---------------------------------------------------------------------------
extern "C" void kernel_launch(void* const* d_in, const int* in_sizes, int n_in,
                              void* d_out, int out_size, void* d_ws, size_t ws_size,
                              hipStream_t stream) {
  const float* Q = (const float*)d_in[0];
  const float* K = (const float*)d_in[1];
  const float* V = (const float*)d_in[2];
  const float* WQ = (const float*)d_in[3];
  const float* WK = (const float*)d_in[4];
  const float* WV = (const float*)d_in[5];
  const float* Wfc = (const float*)d_in[6];
  float* out = (float*)d_out;

  unsigned short* ws = (unsigned short*)d_ws;
  // ws layout (ushort units):
  //   Xb   @ 0         : 3*8388608  (bf16 Q,K,V)      [dead after projections]
  //   ctxr @ 0         : 8388608    (bf16 ctx)        [overlays Xb]
  //   Vt   @ 8388608   : 8388608    (f16 V^T)         [overlays Xb]
  //   Wt   @ 25165824  : 4*1048576  (bf16 W^T: q,k,v,fc)
  //   lin  @ 29360128  : 3*8388608  (bf16 projections)
  unsigned short* Xb = ws;
  unsigned short* ctxr = ws;
  unsigned short* Vt = ws + 8388608;
  unsigned short* Wt = ws + 25165824;
  unsigned short* lin = ws + 29360128;

  convert_x_kernel<<<dim3(4096, 3), 256, 0, stream>>>(Q, K, V, Xb);
  convert_w_kernel<<<dim3(32, 32, 4), 256, 0, stream>>>(WQ, WK, WV, Wfc, Wt);
  const float qscale = 0.125f * 1.4426950408889634f;  // 1/sqrt(dk) * log2(e)
  gemm_bt_kernel<<<dim3(64, 8, 3), 256, 0, stream>>>(Xb, Wt, lin, nullptr, qscale);
  vtrans_kernel<<<dim3(16, 64), 256, 0, stream>>>(lin + 16777216, Vt);
  attn_kernel<<<dim3(64, 8), 256, 0, stream>>>(lin, (const _Float16*)Vt, ctxr);
  gemm_bt_kernel<<<dim3(64, 8, 1), 256, 0, stream>>>(ctxr, Wt + 3 * 1048576, nullptr,
                                                     out, 1.0f);
}

// Round 7
// 352.247 us; speedup vs baseline: 1.4001x; 1.0757x over previous
//
#include <hip/hip_runtime.h>
#include <stdint.h>
#include <math.h>

// ---------------------------------------------------------------------------
// MultiHeadAttention: B=4, S=2048, D=1024, H=16, dk=64
// Raw-reshape head split: head (b,h) = rows [b*2048+h*128, +128) of the
// projected [8192][1024] matrix, reinterpreted as [2048][64].
// R9 = R8 + native v_exp_f32 for all softmax exponentials.
//   The harness compiles WITHOUT -ffast-math, so exp2f() lowers to the OCML
//   library sequence (~6-10 VALU ops w/ denormal scaling). At 64 exps per
//   wave-tile this was the bulk of the unexplained VALUBusy=57% (R8 PMC:
//   ~1600 VALU ops/wave-tile vs ~400 visible). __builtin_amdgcn_exp2f is
//   the bare instruction (1 ulp; softmax-safe).
// Kept from R8: 64 q-rows/wave (2 qg of 32), grid (64,8) = 2 blocks/CU,
// 48KB LDS L2-resident regime (do NOT raise blocks/CU: R6 thrashed L2,
// fetch x4), 32x32x16 MFMA path, K/V fragments read once per tile shared
// by both qg, single-q-per-lane softmax, defer-max THR=8, layout-proof
// P-through-LDS (PV operands share one addressing convention so unknown
// k-slot permutations cancel), pkrtz pack, split-g PV, async
// global_load_lds double-buffered staging, one barrier/tile, LDS-transpose
// epilogue.
// ---------------------------------------------------------------------------

typedef __attribute__((ext_vector_type(8))) short short8;
typedef __attribute__((ext_vector_type(4))) float f32x4;
typedef __attribute__((ext_vector_type(16))) float f32x16;
typedef __attribute__((ext_vector_type(2))) unsigned int u32x2;
typedef __attribute__((ext_vector_type(4))) unsigned int u32x4;
typedef __attribute__((ext_vector_type(8))) _Float16 half8;

__device__ __forceinline__ unsigned short bf16rne(float f) {
  unsigned int u = __builtin_bit_cast(unsigned int, f);
  unsigned int r = u + 0x7FFFu + ((u >> 16) & 1u);
  return (unsigned short)(r >> 16);
}

// async global->LDS, 16B per lane. LDS dest must be wave-uniform base + lane*16.
__device__ __forceinline__ void gld_lds16(const void* g, void* l) {
  typedef __attribute__((address_space(3))) unsigned int lds_u32;
  typedef const __attribute__((address_space(1))) unsigned int glb_u32;
  __builtin_amdgcn_global_load_lds((glb_u32*)(uintptr_t)g,
                                   (lds_u32*)(unsigned int)(uintptr_t)l,
                                   16, 0, 0);
}

// pack two f32 -> one u32 of two f16 (RTZ, single v_cvt_pkrtz_f16_f32)
__device__ __forceinline__ unsigned pkrtz(float a, float b) {
  auto h = __builtin_amdgcn_cvt_pkrtz(a, b);  // __fp16 ext_vector_type(2)
  return __builtin_bit_cast(unsigned, h);
}

// bare v_exp_f32 (2^x). No -ffast-math in harness, so exp2f() would lower
// to the multi-op OCML sequence; this is the single-instruction version.
__device__ __forceinline__ float fexp2(float x) {
#if __has_builtin(__builtin_amdgcn_exp2f)
  return __builtin_amdgcn_exp2f(x);
#else
  float r;
  asm("v_exp_f32 %0, %1" : "=v"(r) : "v"(x));
  return r;
#endif
}

// ---------------------------------------------------------------------------
// fp32 -> bf16 convert for Q,K,V   (3 x 8192 x 1024)
// ---------------------------------------------------------------------------
__global__ void convert_x_kernel(const float* __restrict__ Q,
                                 const float* __restrict__ K,
                                 const float* __restrict__ V,
                                 unsigned short* __restrict__ Xb) {
  const int z = blockIdx.y;
  const float* src = (z == 0) ? Q : (z == 1) ? K : V;
  const size_t i0 = ((size_t)blockIdx.x * 256 + threadIdx.x) * 8;
  const f32x4 a = *(const f32x4*)(src + i0);
  const f32x4 c = *(const f32x4*)(src + i0 + 4);
  u32x4 o;
  o[0] = (unsigned)bf16rne(a[0]) | ((unsigned)bf16rne(a[1]) << 16);
  o[1] = (unsigned)bf16rne(a[2]) | ((unsigned)bf16rne(a[3]) << 16);
  o[2] = (unsigned)bf16rne(c[0]) | ((unsigned)bf16rne(c[1]) << 16);
  o[3] = (unsigned)bf16rne(c[2]) | ((unsigned)bf16rne(c[3]) << 16);
  *(u32x4*)(Xb + (size_t)z * 8388608 + i0) = o;
}

// ---------------------------------------------------------------------------
// W [K=1024][N=1024] fp32 -> Wt [N][K] bf16 (transposed so GEMMs are A*B^T)
// ---------------------------------------------------------------------------
__global__ void convert_w_kernel(const float* __restrict__ W0,
                                 const float* __restrict__ W1,
                                 const float* __restrict__ W2,
                                 const float* __restrict__ W3,
                                 unsigned short* __restrict__ Wt) {
  const int z = blockIdx.z;
  const float* W = (z == 0) ? W0 : (z == 1) ? W1 : (z == 2) ? W2 : W3;
  unsigned short* dst = Wt + (size_t)z * 1048576;
  __shared__ float tile[32][33];
  const int tx = threadIdx.x & 31, ty = threadIdx.x >> 5;
  const int k0 = blockIdx.x * 32, n0 = blockIdx.y * 32;
#pragma unroll
  for (int yy = 0; yy < 32; yy += 8)
    tile[ty + yy][tx] = W[(size_t)(k0 + ty + yy) * 1024 + n0 + tx];
  __syncthreads();
#pragma unroll
  for (int yy = 0; yy < 32; yy += 8)
    dst[(size_t)(n0 + ty + yy) * 1024 + k0 + tx] = bf16rne(tile[tx][ty + yy]);
}

// ---------------------------------------------------------------------------
// GEMM (m97 structure): C[z] = A[z][8192x1024] * Bt[z][1024x1024]^T
// ---------------------------------------------------------------------------
__global__ __launch_bounds__(256, 2) void gemm_bt_kernel(
    const unsigned short* __restrict__ A, const unsigned short* __restrict__ Bt,
    unsigned short* __restrict__ Cbf, float* __restrict__ Cf32, float scaleZ0) {
  constexpr int K = 1024, N = 1024;
  const int z = blockIdx.z;
  const unsigned short* Ab = A + (size_t)z * 8192 * 1024;
  const unsigned short* Bb = Bt + (size_t)z * 1024 * 1024;
  const int tid = threadIdx.x;
  const int lane = tid & 63;
  const int w = tid >> 6;
  const int l15 = lane & 15, quad = lane >> 4;
  const int rowBase = blockIdx.x * 128;
  const int colBase = blockIdx.y * 128;
  const int wrow = (w >> 1) * 64;
  const int wcol = (w & 1) * 64;
  __shared__ __align__(16) unsigned short As[128 * 32];
  __shared__ __align__(16) unsigned short Bs[128 * 32];

  const f32x4 z4 = {0.0f, 0.0f, 0.0f, 0.0f};
  f32x4 acc[4][4];
#pragma unroll
  for (int i = 0; i < 4; i++)
#pragma unroll
    for (int j = 0; j < 4; j++) acc[i][j] = z4;

  const int s0 = tid, s1 = tid + 256;
  const int rA0 = s0 >> 2, cA0 = (s0 & 3) * 8;
  const int rA1 = s1 >> 2, cA1 = (s1 & 3) * 8;

  for (int k0 = 0; k0 < K; k0 += 32) {
    gld_lds16(Ab + (size_t)(rowBase + rA0) * K + k0 + cA0, (void*)(As + s0 * 8));
    gld_lds16(Ab + (size_t)(rowBase + rA1) * K + k0 + cA1, (void*)(As + s1 * 8));
    gld_lds16(Bb + (size_t)(colBase + rA0) * K + k0 + cA0, (void*)(Bs + s0 * 8));
    gld_lds16(Bb + (size_t)(colBase + rA1) * K + k0 + cA1, (void*)(Bs + s1 * 8));
    __syncthreads();
    short8 af[4], bfr[4];
#pragma unroll
    for (int i = 0; i < 4; i++)
      af[i] = *(const short8*)(As + (wrow + i * 16 + l15) * 32 + quad * 8);
#pragma unroll
    for (int j = 0; j < 4; j++)
      bfr[j] = *(const short8*)(Bs + (wcol + j * 16 + l15) * 32 + quad * 8);
#pragma unroll
    for (int i = 0; i < 4; i++)
#pragma unroll
      for (int j = 0; j < 4; j++)
        acc[i][j] =
            __builtin_amdgcn_mfma_f32_16x16x32_bf16(af[i], bfr[j], acc[i][j], 0, 0, 0);
    __syncthreads();
  }

  const float sc = (z == 0) ? scaleZ0 : 1.0f;
#pragma unroll
  for (int i = 0; i < 4; i++) {
#pragma unroll
    for (int j = 0; j < 4; j++) {
#pragma unroll
      for (int r = 0; r < 4; r++) {
        const int row = rowBase + wrow + i * 16 + quad * 4 + r;
        const int col = colBase + wcol + j * 16 + l15;
        const float v = acc[i][j][r] * sc;
        if (Cbf != nullptr) {
          Cbf[(size_t)z * 8192 * 1024 + (size_t)row * N + col] = bf16rne(v);
        } else {
          Cf32[(size_t)row * N + col] = v;
        }
      }
    }
  }
}

// ---------------------------------------------------------------------------
// V transpose: lin_v head (b,h) [2048][64] bf16 -> Vt[bh][64][2048] f16.
// ---------------------------------------------------------------------------
__global__ void vtrans_kernel(const unsigned short* __restrict__ linv,
                              unsigned short* __restrict__ Vt) {
  const int st = blockIdx.x, bh = blockIdx.y;
  const unsigned short* vp = linv + (size_t)bh * 131072;
  __shared__ unsigned short tile[64 * 136];
  const int tid = threadIdx.x;
#pragma unroll
  for (int it = 0; it < 4; it++) {
    const int idx = it * 256 + tid;        // 0..1023
    const int s = idx >> 3, d0 = (idx & 7) * 8;
    const u32x4 vv = *(const u32x4*)(vp + (size_t)(st * 128 + s) * 64 + d0);
#pragma unroll
    for (int m = 0; m < 4; m++) {
      const unsigned lo = vv[m] & 0xffffu, hi = vv[m] >> 16;
      const float f0 = __builtin_bit_cast(float, lo << 16);
      const float f1 = __builtin_bit_cast(float, hi << 16);
      const _Float16 h0 = (_Float16)f0, h1 = (_Float16)f1;
      tile[(d0 + 2 * m) * 136 + s] = __builtin_bit_cast(unsigned short, h0);
      tile[(d0 + 2 * m + 1) * 136 + s] = __builtin_bit_cast(unsigned short, h1);
    }
  }
  __syncthreads();
#pragma unroll
  for (int it = 0; it < 4; it++) {
    const int idx = it * 256 + tid;
    const int d = idx >> 4, s0 = (idx & 15) * 8;
    const u32x4 o = *(const u32x4*)(tile + d * 136 + s0);
    *(u32x4*)(Vt + (size_t)bh * 131072 + (size_t)d * 2048 + st * 128 + s0) = o;
  }
}

// ---------------------------------------------------------------------------
// Flash attention, 32x32 MFMA path, async-LDS double-buffered, 64 q/wave.
// Grid (bh=64, qt=8); block 256 = 4 waves; wave w owns q-rows
// [qt*256 + w*64, +64) as two q-groups qg=0,1 of 32; lane's q = qg*32+l31.
// LDS 48KB (2 resident blocks/CU -- L2-resident regime; DO NOT raise
// blocks/CU: R6 thrashed L2, fetch 45->198MB).
// Ks [2][64 key][64 dk] bf16 16KB + Vs [2][64 d][64 key] f16 16KB (both
// XOR-swizzled 16B segs, seg^(row&7)) + per-wave P tile [32 q][64 key] f16
// 4KB x4 = 16KB (reused across qg; same-wave LDS is in-order).
// S^T = mfma_32x32x16_bf16(K, Q): C col = q = l31, row = key =
// (r&3)+8*(r>>2)+4*(l>>5)  [HW-verified layout].
// K/V fragments read ONCE per tile, used by both q-groups.
// PV per 32-key group g: P packed (pkrtz) and ds_written at its true key
// index, read back as B-fragments with the SAME convention as the V
// A-fragments (unknown k-slot permutations cancel between PV operands).
// ---------------------------------------------------------------------------
__global__ __launch_bounds__(256, 2) void attn_kernel(
    const unsigned short* __restrict__ lin, const _Float16* __restrict__ Vt,
    unsigned short* __restrict__ ctxr) {
  const int bh = blockIdx.x;
  const int qt = blockIdx.y;
  const int b = bh >> 4, h = bh & 15;
  const int tid = threadIdx.x, lane = tid & 63, w = tid >> 6;
  const int l31 = lane & 31, hl = lane >> 5, x7 = l31 & 7;
  const size_t headOff = (size_t)(b * 2048 + h * 128) * 1024;
  const unsigned short* qp = lin + headOff;
  const unsigned short* kp = lin + 8388608 + headOff;
  const _Float16* vtp = Vt + (size_t)bh * 131072;

  __shared__ __align__(16) unsigned short smem[24576];  // 48 KB
  unsigned short(*Ks)[4096] = (unsigned short(*)[4096])smem;     // [2][4096]
  _Float16(*Vs)[4096] = (_Float16(*)[4096])(smem + 8192);        // [2][4096]
  _Float16* Pl = (_Float16*)(smem + 16384) + w * 2048;           // [32][64]

  // Staging geometry: waves 0,1 stage K (512 slots); waves 2,3 stage V.
  const int stageV = (w >= 2);
  const int wbase = (stageV ? (w - 2) : w) * 256 + lane;
  auto stage = [&](int bufn, int key0) {
#pragma unroll
    for (int i = 0; i < 4; i++) {
      const int slot = wbase + i * 64;
      const int row = slot >> 3;                 // key (K) or d (V)
      const int seg = (slot & 7) ^ (row & 7);    // un-swizzled segment
      if (!stageV) {
        gld_lds16(kp + (size_t)(key0 + row) * 64 + seg * 8,
                  (void*)(&Ks[bufn][slot * 8]));
      } else {
        gld_lds16(vtp + (size_t)row * 2048 + key0 + seg * 8,
                  (void*)(&Vs[bufn][slot * 8]));
      }
    }
  };

  // Q B-fragments (col = q = l31, k-window ks*16 + hl*8) for both q-groups.
  const int qrow0 = qt * 256 + w * 64;
  short8 bq[2][4];
#pragma unroll
  for (int qg = 0; qg < 2; qg++)
#pragma unroll
    for (int ks = 0; ks < 4; ks++)
      bq[qg][ks] = *(const short8*)(qp +
                                    (size_t)(qrow0 + qg * 32 + l31) * 64 +
                                    ks * 16 + hl * 8);

  f32x16 z16;
#pragma unroll
  for (int r = 0; r < 16; r++) z16[r] = 0.0f;
  f32x16 co[2][2] = {{z16, z16}, {z16, z16}};  // [qg][dt]
  float mrun[2] = {-INFINITY, -INFINITY};
  float lrun[2] = {0.0f, 0.0f};

  stage(0, 0);
  __syncthreads();

  for (int kt = 0; kt < 32; kt++) {
    const int cur = kt & 1;
    if (kt < 31) stage(cur ^ 1, (kt + 1) * 64);

    // ---- K fragments ONCE (8x ds_read_b128), shared by both q-groups.
    short8 kf[2][4];
#pragma unroll
    for (int g = 0; g < 2; g++)
#pragma unroll
      for (int ks = 0; ks < 4; ks++) {
        const int slot = (g * 32 + l31) * 8 + ((2 * ks + hl) ^ x7);
        kf[g][ks] = *(const short8*)(&Ks[cur][slot * 8]);
      }

    // ---- S^T: 16x mfma_32x32x16_bf16 (2 qg x 2 key-groups x 4 dk-steps)
    f32x16 sacc[2][2] = {{z16, z16}, {z16, z16}};  // [qg][g]
    __builtin_amdgcn_s_setprio(1);
#pragma unroll
    for (int qg = 0; qg < 2; qg++)
#pragma unroll
      for (int g = 0; g < 2; g++)
#pragma unroll
        for (int ks = 0; ks < 4; ks++)
          sacc[qg][g] = __builtin_amdgcn_mfma_f32_32x32x16_bf16(
              kf[g][ks], bq[qg][ks], sacc[qg][g], 0, 0, 0);
    __builtin_amdgcn_s_setprio(0);

    // ---- V A-fragments ONCE (8x ds_read_b128), shared by both q-groups.
    half8 vf[2][2][2];  // [dt][g][s]
#pragma unroll
    for (int dt = 0; dt < 2; dt++)
#pragma unroll
      for (int g = 0; g < 2; g++)
#pragma unroll
        for (int s = 0; s < 2; s++) {
          const int slot = (dt * 32 + l31) * 8 + ((4 * g + 2 * s + hl) ^ x7);
          vf[dt][g][s] = *(const half8*)(&Vs[cur][slot * 8]);
        }

    // ---- per q-group: softmax + P pack/write/read + PV
#pragma unroll
    for (int qg = 0; qg < 2; qg++) {
      float pmax;
      {
        float tm[8];
#pragma unroll
        for (int r = 0; r < 8; r++)
          tm[r] = fmaxf(fmaxf(sacc[qg][0][r], sacc[qg][0][r + 8]),
                        fmaxf(sacc[qg][1][r], sacc[qg][1][r + 8]));
        const float a0 = fmaxf(fmaxf(tm[0], tm[1]), fmaxf(tm[2], tm[3]));
        const float a1 = fmaxf(fmaxf(tm[4], tm[5]), fmaxf(tm[6], tm[7]));
        pmax = fmaxf(a0, a1);
      }
      pmax = fmaxf(pmax, __shfl_xor(pmax, 32, 64));
      if (!__all(pmax - mrun[qg] <= 8.0f)) {  // defer-max
        const float mnew = fmaxf(mrun[qg], pmax);
        const float a = fexp2(mrun[qg] - mnew);
        mrun[qg] = mnew;
        lrun[qg] *= a;
#pragma unroll
        for (int r = 0; r < 16; r++) {
          co[qg][0][r] *= a;
          co[qg][1][r] *= a;
        }
      }
      float ls0 = 0.0f, ls1 = 0.0f, ls2 = 0.0f, ls3 = 0.0f;
#pragma unroll
      for (int g = 0; g < 2; g++) {
#pragma unroll
        for (int r = 0; r < 16; r += 4) {
          const float p0 = fexp2(sacc[qg][g][r + 0] - mrun[qg]);
          const float p1 = fexp2(sacc[qg][g][r + 1] - mrun[qg]);
          const float p2 = fexp2(sacc[qg][g][r + 2] - mrun[qg]);
          const float p3 = fexp2(sacc[qg][g][r + 3] - mrun[qg]);
          sacc[qg][g][r + 0] = p0;
          sacc[qg][g][r + 1] = p1;
          sacc[qg][g][r + 2] = p2;
          sacc[qg][g][r + 3] = p3;
          ls0 += p0;
          ls1 += p1;
          ls2 += p2;
          ls3 += p3;
        }
      }
      lrun[qg] += (ls0 + ls1) + (ls2 + ls3);

      // P -> per-wave LDS tile at true key index (C-layout key_in_grp =
      // 8rg+4hl+t), then B-fragments with the V A-fragment convention;
      // g's MFMAs overlap g+1's pack. Pl reused across qg (in-order LDS).
#pragma unroll
      for (int g = 0; g < 2; g++) {
#pragma unroll
        for (int rg = 0; rg < 4; rg++) {
          u32x2 pw;
          pw[0] = pkrtz(sacc[qg][g][4 * rg + 0], sacc[qg][g][4 * rg + 1]);
          pw[1] = pkrtz(sacc[qg][g][4 * rg + 2], sacc[qg][g][4 * rg + 3]);
          *(u32x2*)(Pl + l31 * 64 + (((4 * g + rg) ^ x7) * 8) + hl * 4) = pw;
        }
        half8 pf[2];
#pragma unroll
        for (int s = 0; s < 2; s++)
          pf[s] =
              *(const half8*)(Pl + l31 * 64 + (((4 * g + 2 * s + hl) ^ x7) * 8));
        __builtin_amdgcn_s_setprio(1);
#pragma unroll
        for (int dt = 0; dt < 2; dt++)
#pragma unroll
          for (int s = 0; s < 2; s++)
            co[qg][dt] = __builtin_amdgcn_mfma_f32_32x32x16_f16(
                vf[dt][g][s], pf[s], co[qg][dt], 0, 0, 0);
        __builtin_amdgcn_s_setprio(0);
      }
    }
    __syncthreads();  // drains stage loads; separates buffer reuse
  }

  // ---- epilogue: normalize, transpose via LDS, coalesced b128 stores.
  unsigned short* Cw = smem + w * 4608;  // per-wave 64 rows x stride 72
#pragma unroll
  for (int qg = 0; qg < 2; qg++) {
    const float l = lrun[qg] + __shfl_xor(lrun[qg], 32, 64);
    const float inv = 1.0f / l;
#pragma unroll
    for (int dt = 0; dt < 2; dt++) {
#pragma unroll
      for (int r = 0; r < 16; r++) {
        const int d = dt * 32 + (r & 3) + 8 * (r >> 2) + 4 * hl;
        Cw[(qg * 32 + l31) * 72 + d] = bf16rne(co[qg][dt][r] * inv);
      }
    }
  }
  __syncthreads();
#pragma unroll
  for (int it = 0; it < 8; it++) {
    const int q = it * 8 + (lane >> 3);
    const int seg = lane & 7;
    const u32x4 o = *(const u32x4*)(Cw + q * 72 + seg * 8);
    *(u32x4*)(ctxr + (size_t)(b * 2048 + qrow0 + q) * 1024 + h * 64 + seg * 8) = o;
  }
}

// ---------------------------------------------------------------------------
extern "C" void kernel_launch(void* const* d_in, const int* in_sizes, int n_in,
                              void* d_out, int out_size, void* d_ws, size_t ws_size,
                              hipStream_t stream) {
  const float* Q = (const float*)d_in[0];
  const float* K = (const float*)d_in[1];
  const float* V = (const float*)d_in[2];
  const float* WQ = (const float*)d_in[3];
  const float* WK = (const float*)d_in[4];
  const float* WV = (const float*)d_in[5];
  const float* Wfc = (const float*)d_in[6];
  float* out = (float*)d_out;

  unsigned short* ws = (unsigned short*)d_ws;
  // ws layout (ushort units):
  //   Xb   @ 0         : 3*8388608  (bf16 Q,K,V)      [dead after projections]
  //   ctxr @ 0         : 8388608    (bf16 ctx)        [overlays Xb]
  //   Vt   @ 8388608   : 8388608    (f16 V^T)         [overlays Xb]
  //   Wt   @ 25165824  : 4*1048576  (bf16 W^T: q,k,v,fc)
  //   lin  @ 29360128  : 3*8388608  (bf16 projections)
  unsigned short* Xb = ws;
  unsigned short* ctxr = ws;
  unsigned short* Vt = ws + 8388608;
  unsigned short* Wt = ws + 25165824;
  unsigned short* lin = ws + 29360128;

  convert_x_kernel<<<dim3(4096, 3), 256, 0, stream>>>(Q, K, V, Xb);
  convert_w_kernel<<<dim3(32, 32, 4), 256, 0, stream>>>(WQ, WK, WV, Wfc, Wt);
  const float qscale = 0.125f * 1.4426950408889634f;  // 1/sqrt(dk) * log2(e)
  gemm_bt_kernel<<<dim3(64, 8, 3), 256, 0, stream>>>(Xb, Wt, lin, nullptr, qscale);
  vtrans_kernel<<<dim3(16, 64), 256, 0, stream>>>(lin + 16777216, Vt);
  attn_kernel<<<dim3(64, 8), 256, 0, stream>>>(lin, (const _Float16*)Vt, ctxr);
  gemm_bt_kernel<<<dim3(64, 8, 1), 256, 0, stream>>>(ctxr, Wt + 3 * 1048576, nullptr,
                                                     out, 1.0f);
}